// Round 20
// baseline (657.919 us; speedup 1.0000x reference)
//
#include <hip/hip_runtime.h>
#include <hip/hip_bf16.h>
#include <math.h>

#define H 128
#define EPS_BN 1e-5f
#define RSTATS 16

typedef __attribute__((ext_vector_type(8))) short short8;
typedef __attribute__((ext_vector_type(4))) float f32x4;
typedef unsigned long long ull;

__device__ __forceinline__ float bf2f(ushort u){
  union { float f; uint v; } x; x.v = ((uint)u) << 16; return x.f;
}
__device__ __forceinline__ ushort f2bf(float f){
  union { float f; uint v; } x; x.f = f;
  uint v = x.v;
  uint r = v + 0x7fff + ((v >> 16) & 1);   // RNE
  return (ushort)(r >> 16);
}

// nontemporal (no-allocate) edge-record load: edge stream is read once/layer
__device__ __forceinline__ uint2 ldnt2(const uint2* p){
  ull v = __builtin_nontemporal_load((const ull*)p);
  return make_uint2((uint)v, (uint)(v >> 32));
}
__device__ __forceinline__ uint4 ldnt4(const uint4* p){
  const ull* q = (const ull*)p;
  ull a = __builtin_nontemporal_load(q);
  ull b = __builtin_nontemporal_load(q + 1);
  return make_uint4((uint)a, (uint)(a >> 32), (uint)b, (uint)(b >> 32));
}

__device__ __forceinline__ void acc8(float* a, uint4 v, float wt){
  a[0] += wt*bf2f((ushort)(v.x & 0xffff)); a[1] += wt*bf2f((ushort)(v.x >> 16));
  a[2] += wt*bf2f((ushort)(v.y & 0xffff)); a[3] += wt*bf2f((ushort)(v.y >> 16));
  a[4] += wt*bf2f((ushort)(v.z & 0xffff)); a[5] += wt*bf2f((ushort)(v.z >> 16));
  a[6] += wt*bf2f((ushort)(v.w & 0xffff)); a[7] += wt*bf2f((ushort)(v.w >> 16));
}
// BN+ReLU applied to the loaded row before accumulation
__device__ __forceinline__ void acc8bn(float* a, uint4 v, float wt,
                                       const float* sc, const float* sh){
  float z[8] = { bf2f((ushort)(v.x & 0xffff)), bf2f((ushort)(v.x >> 16)),
                 bf2f((ushort)(v.y & 0xffff)), bf2f((ushort)(v.y >> 16)),
                 bf2f((ushort)(v.z & 0xffff)), bf2f((ushort)(v.z >> 16)),
                 bf2f((ushort)(v.w & 0xffff)), bf2f((ushort)(v.w >> 16)) };
  #pragma unroll
  for (int j = 0; j < 8; ++j){
    float y = fmaxf(fmaf(z[j], sc[j], sh[j]), 0.f);
    a[j] = fmaf(wt, y, a[j]);
  }
}

// ---------------- CSR build (simple single-pass) ----------------

__global__ void k_count(const int* __restrict__ col, int E, int* __restrict__ cnt){
  int i = blockIdx.x*blockDim.x + threadIdx.x;
  if (i < E){
    int c = __builtin_nontemporal_load(col + i);
    atomicAdd(&cnt[c], 1);
  }
}

__global__ void k_scan1(const int* __restrict__ cnt, int* __restrict__ off,
                        int* __restrict__ bsum, float* __restrict__ dinv, int n){
  __shared__ int s[1024];
  int t = threadIdx.x;
  int i = blockIdx.x*1024 + t;
  int v = (i < n) ? cnt[i] : 0;
  if (i < n) dinv[i] = rsqrtf((float)v + 1.0f);   // +1 self-loop
  s[t] = v; __syncthreads();
  for (int d = 1; d < 1024; d <<= 1){
    int x = (t >= d) ? s[t-d] : 0;
    __syncthreads();
    s[t] += x;
    __syncthreads();
  }
  if (i < n) off[i] = s[t] - v;
  if (t == 1023) bsum[blockIdx.x] = s[1023];
}

__global__ void k_scan2(int* bsum, int nb){
  int l = threadIdx.x;           // 64 threads, 1 block
  int carry = 0;
  for (int b0 = 0; b0 < nb; b0 += 64){
    int i = b0 + l;
    int orig = (i < nb) ? bsum[i] : 0;
    int v = orig;
    #pragma unroll
    for (int d = 1; d < 64; d <<= 1){
      int x = __shfl_up(v, d);
      if (l >= d) v += x;
    }
    if (i < nb) bsum[i] = carry + v - orig;   // exclusive
    carry += __shfl(v, 63);
  }
}

__global__ void k_scan3(int* __restrict__ off, int* __restrict__ cursor,
                        const int* __restrict__ bsum, int n, int Etot){
  int i = blockIdx.x*blockDim.x + threadIdx.x;
  if (i < n){ int o = off[i] + bsum[i >> 10]; off[i] = o; cursor[i] = o; }
  if (i == 0) off[n] = Etot;
}

// edge record = {permuted source row, weight}; NONTEMPORAL store (no-allocate)
__global__ void k_fill(const int* __restrict__ row, const int* __restrict__ col, int E,
                       const float* __restrict__ dinv, const int* __restrict__ iperm,
                       int* __restrict__ cursor, uint2* __restrict__ edge){
  int i = blockIdx.x*blockDim.x + threadIdx.x;
  if (i < E){
    int c = __builtin_nontemporal_load(col + i);
    int r = __builtin_nontemporal_load(row + i);
    int p = atomicAdd(&cursor[c], 1);
    ull v = ((ull)__float_as_uint(dinv[r]*dinv[c]) << 32) | (ull)(uint)iperm[r];
    __builtin_nontemporal_store(v, (ull*)(edge + p));
  }
}

// -------- degree-sort permutation (DESCENDING): LDS-aggregated counting sort --

__global__ __launch_bounds__(1024) void k_dhist(
    const int* __restrict__ cnt, int* __restrict__ dh, int n){
  __shared__ int lh[256];
  int t = threadIdx.x;
  if (t < 256) lh[t] = 0;
  __syncthreads();
  int i = blockIdx.x*1024 + t;
  if (i < n){
    int d = cnt[i]; if (d > 255) d = 255;
    atomicAdd(&lh[d], 1);
  }
  __syncthreads();
  if (t < 256 && lh[t]) atomicAdd(&dh[t], lh[t]);
}

__global__ void k_dscan(int* __restrict__ dh){   // 1 block, 256 thr; DESC offsets
  __shared__ int s[256];
  int t = threadIdx.x;
  int v = dh[255 - t];              // reversed order
  s[t] = v; __syncthreads();
  for (int d = 1; d < 256; d <<= 1){
    int x = (t >= d) ? s[t-d] : 0;
    __syncthreads();
    s[t] += x;
    __syncthreads();
  }
  dh[255 - t] = s[t] - v;   // bin d offset = count of nodes with degree > d
}

__global__ __launch_bounds__(1024) void k_dperm(
    const int* __restrict__ cnt, int* __restrict__ dh,
    int* __restrict__ perm, int* __restrict__ iperm, int n){
  __shared__ int lh[256];
  __shared__ int lbase[256];
  int t = threadIdx.x;
  if (t < 256) lh[t] = 0;
  __syncthreads();
  int i = blockIdx.x*1024 + t;
  int d = 0, li = 0;
  if (i < n){
    d = cnt[i]; if (d > 255) d = 255;
    li = atomicAdd(&lh[d], 1);
  }
  __syncthreads();
  if (t < 256){
    int c = lh[t];
    lbase[t] = c ? atomicAdd(&dh[t], c) : 0;
  }
  __syncthreads();
  if (i < n){
    int pos = lbase[d] + li;
    perm[pos] = i;
    iperm[i] = pos;
  }
}

// ---------------- weight prep: bf16, transposed, beta-folded ----------------

__global__ void k_prepw(const float* __restrict__ lin0_w, const float* __restrict__ conv_w,
                        ushort* __restrict__ lin0T, ushort* __restrict__ WpT,
                        float b0, float b1, float b2, float b3){
  int i = blockIdx.x*blockDim.x + threadIdx.x;
  if (i < 128*256){
    int nn = i >> 8, k = i & 255;
    lin0T[i] = f2bf(lin0_w[k*128 + nn]);
  } else if (i < 128*256 + 4*128*128){
    int j = i - 128*256;
    int ll = j >> 14, rc = j & 16383;
    int nn = rc >> 7, k = rc & 127;
    float beta = (ll==0)?b0:(ll==1)?b1:(ll==2)?b2:b3;
    float v = beta * conv_w[ll*16384 + k*128 + nn];
    if (k == nn) v += 1.0f - beta;
    WpT[j] = f2bf(v);
  }
}

// ---------------- gather cores: one quad (16 lanes) per node ----------------
// 8-wide unroll; edge records loaded NONTEMPORAL (streamed once per layer).

__device__ __forceinline__ void gather_edges(
    float* a, const ushort* __restrict__ zin, const uint2* __restrict__ edge,
    int e0, int e1, int lr){
  int e = e0;
  for (; e + 7 < e1; e += 8){
    uint2 er0 = ldnt2(edge+e),   er1 = ldnt2(edge+e+1);
    uint2 er2 = ldnt2(edge+e+2), er3 = ldnt2(edge+e+3);
    uint2 er4 = ldnt2(edge+e+4), er5 = ldnt2(edge+e+5);
    uint2 er6 = ldnt2(edge+e+6), er7 = ldnt2(edge+e+7);
    uint4 v0 = *(const uint4*)(zin + (size_t)er0.x*H + lr*8);
    uint4 v1 = *(const uint4*)(zin + (size_t)er1.x*H + lr*8);
    uint4 v2 = *(const uint4*)(zin + (size_t)er2.x*H + lr*8);
    uint4 v3 = *(const uint4*)(zin + (size_t)er3.x*H + lr*8);
    uint4 v4 = *(const uint4*)(zin + (size_t)er4.x*H + lr*8);
    uint4 v5 = *(const uint4*)(zin + (size_t)er5.x*H + lr*8);
    uint4 v6 = *(const uint4*)(zin + (size_t)er6.x*H + lr*8);
    uint4 v7 = *(const uint4*)(zin + (size_t)er7.x*H + lr*8);
    acc8(a, v0, __uint_as_float(er0.y));
    acc8(a, v1, __uint_as_float(er1.y));
    acc8(a, v2, __uint_as_float(er2.y));
    acc8(a, v3, __uint_as_float(er3.y));
    acc8(a, v4, __uint_as_float(er4.y));
    acc8(a, v5, __uint_as_float(er5.y));
    acc8(a, v6, __uint_as_float(er6.y));
    acc8(a, v7, __uint_as_float(er7.y));
  }
  for (; e + 3 < e1; e += 4){
    uint2 er0 = ldnt2(edge+e),   er1 = ldnt2(edge+e+1);
    uint2 er2 = ldnt2(edge+e+2), er3 = ldnt2(edge+e+3);
    uint4 v0 = *(const uint4*)(zin + (size_t)er0.x*H + lr*8);
    uint4 v1 = *(const uint4*)(zin + (size_t)er1.x*H + lr*8);
    uint4 v2 = *(const uint4*)(zin + (size_t)er2.x*H + lr*8);
    uint4 v3 = *(const uint4*)(zin + (size_t)er3.x*H + lr*8);
    acc8(a, v0, __uint_as_float(er0.y));
    acc8(a, v1, __uint_as_float(er1.y));
    acc8(a, v2, __uint_as_float(er2.y));
    acc8(a, v3, __uint_as_float(er3.y));
  }
  for (; e < e1; ++e){
    uint2 er = ldnt2(edge+e);
    uint4 v = *(const uint4*)(zin + (size_t)er.x*H + lr*8);
    acc8(a, v, __uint_as_float(er.y));
  }
}

__device__ __forceinline__ void gather_edges_bn(
    float* a, const ushort* __restrict__ zin, const uint2* __restrict__ edge,
    int e0, int e1, int lr, const float* sc, const float* sh){
  int e = e0;
  for (; e + 7 < e1; e += 8){
    uint2 er0 = ldnt2(edge+e),   er1 = ldnt2(edge+e+1);
    uint2 er2 = ldnt2(edge+e+2), er3 = ldnt2(edge+e+3);
    uint2 er4 = ldnt2(edge+e+4), er5 = ldnt2(edge+e+5);
    uint2 er6 = ldnt2(edge+e+6), er7 = ldnt2(edge+e+7);
    uint4 v0 = *(const uint4*)(zin + (size_t)er0.x*H + lr*8);
    uint4 v1 = *(const uint4*)(zin + (size_t)er1.x*H + lr*8);
    uint4 v2 = *(const uint4*)(zin + (size_t)er2.x*H + lr*8);
    uint4 v3 = *(const uint4*)(zin + (size_t)er3.x*H + lr*8);
    uint4 v4 = *(const uint4*)(zin + (size_t)er4.x*H + lr*8);
    uint4 v5 = *(const uint4*)(zin + (size_t)er5.x*H + lr*8);
    uint4 v6 = *(const uint4*)(zin + (size_t)er6.x*H + lr*8);
    uint4 v7 = *(const uint4*)(zin + (size_t)er7.x*H + lr*8);
    acc8bn(a, v0, __uint_as_float(er0.y), sc, sh);
    acc8bn(a, v1, __uint_as_float(er1.y), sc, sh);
    acc8bn(a, v2, __uint_as_float(er2.y), sc, sh);
    acc8bn(a, v3, __uint_as_float(er3.y), sc, sh);
    acc8bn(a, v4, __uint_as_float(er4.y), sc, sh);
    acc8bn(a, v5, __uint_as_float(er5.y), sc, sh);
    acc8bn(a, v6, __uint_as_float(er6.y), sc, sh);
    acc8bn(a, v7, __uint_as_float(er7.y), sc, sh);
  }
  for (; e + 3 < e1; e += 4){
    uint2 er0 = ldnt2(edge+e),   er1 = ldnt2(edge+e+1);
    uint2 er2 = ldnt2(edge+e+2), er3 = ldnt2(edge+e+3);
    uint4 v0 = *(const uint4*)(zin + (size_t)er0.x*H + lr*8);
    uint4 v1 = *(const uint4*)(zin + (size_t)er1.x*H + lr*8);
    uint4 v2 = *(const uint4*)(zin + (size_t)er2.x*H + lr*8);
    uint4 v3 = *(const uint4*)(zin + (size_t)er3.x*H + lr*8);
    acc8bn(a, v0, __uint_as_float(er0.y), sc, sh);
    acc8bn(a, v1, __uint_as_float(er1.y), sc, sh);
    acc8bn(a, v2, __uint_as_float(er2.y), sc, sh);
    acc8bn(a, v3, __uint_as_float(er3.y), sc, sh);
  }
  for (; e < e1; ++e){
    uint2 er = ldnt2(edge+e);
    uint4 v = *(const uint4*)(zin + (size_t)er.x*H + lr*8);
    acc8bn(a, v, __uint_as_float(er.y), sc, sh);
  }
}

// ---------------- input-layer prop: x0 = agg(xw)+b ; permuted layout --------

__global__ __launch_bounds__(256) void k_prop0(
    const ushort* __restrict__ h, const int* __restrict__ off,
    const uint2* __restrict__ edge, const float* __restrict__ dinv,
    const float* __restrict__ bias, const int* __restrict__ perm,
    ushort* __restrict__ x0, int n){
  int pq = (blockIdx.x*blockDim.x + threadIdx.x) >> 4;   // permuted row
  if (pq >= n) return;
  int gq = perm[pq];                 // original node (off/dinv)
  int lr = threadIdx.x & 15;
  float a[8];
  #pragma unroll
  for (int j = 0; j < 8; ++j) a[j] = 0.f;
  float wc = dinv[gq]; wc *= wc;
  uint4 vs = *(const uint4*)(h + (size_t)pq*H + lr*8);   // self: permuted row
  gather_edges(a, h, edge, off[gq], off[gq+1], lr);
  acc8(a, vs, wc);
  float4 b0 = *(const float4*)(bias + lr*8);
  float4 b1 = *(const float4*)(bias + lr*8 + 4);
  uint4 pk;
  pk.x = (uint)f2bf(a[0]+b0.x) | ((uint)f2bf(a[1]+b0.y) << 16);
  pk.y = (uint)f2bf(a[2]+b0.z) | ((uint)f2bf(a[3]+b0.w) << 16);
  pk.z = (uint)f2bf(a[4]+b1.x) | ((uint)f2bf(a[5]+b1.y) << 16);
  pk.w = (uint)f2bf(a[6]+b1.z) | ((uint)f2bf(a[7]+b1.w) << 16);
  *(uint4*)(x0 + (size_t)pq*H + lr*8) = pk;              // contiguous write
}

// ---------------- fused layer: [BN+ReLU ->] prop -> MFMA GEMM -> z (+stats) --

template<bool BNIN, bool STATS, bool OUTF32, bool SAMEX0>
__global__ __launch_bounds__(256) void k_layer(
    const ushort* __restrict__ zin, const ushort* __restrict__ x0,
    const int* __restrict__ off, const uint2* __restrict__ edge,
    const float* __restrict__ dinv, const ushort* __restrict__ BT,
    const int* __restrict__ perm, const float* __restrict__ scsh,
    void* __restrict__ zout, float* __restrict__ stats, int n)
{
  __shared__ ushort Sm[32*128];   // swizzled s tile: row*128 + ((blk16^(row&15))*8)
  __shared__ int pm[32];
  int t = threadIdx.x;
  int w = t >> 6, l = t & 63;
  int lr = l & 15, q = l >> 4;
  int base = blockIdx.x * 32;
  if (t < 32) pm[t] = (base + t < n) ? perm[base + t] : -1;

  float sc[8], sh[8];
  if (BNIN){
    #pragma unroll
    for (int j = 0; j < 8; ++j){
      sc[j] = scsh[lr*8 + j];
      sh[j] = scsh[128 + lr*8 + j];
    }
  }
  __syncthreads();

  // ---- prop phase: quad-per-node, 2 nodes per quad ----
  #pragma unroll
  for (int g2 = 0; g2 < 2; ++g2){
    int row  = w*8 + g2*4 + q;
    int node = pm[row];             // original id (off/dinv only)
    int grow = base + row;          // permuted row (addresses)
    float a[8];
    #pragma unroll
    for (int j = 0; j < 8; ++j) a[j] = 0.f;
    uint4 pk = make_uint4(0u,0u,0u,0u);
    if (node >= 0){
      float wc = dinv[node]; wc *= wc;
      uint4 vs = *(const uint4*)(zin + (size_t)grow*H + lr*8);
      if (BNIN){
        gather_edges_bn(a, zin, edge, off[node], off[node+1], lr, sc, sh);
        acc8bn(a, vs, wc, sc, sh);
      } else {
        gather_edges(a, zin, edge, off[node], off[node+1], lr);
        acc8(a, vs, wc);
      }
      uint4 xv = SAMEX0 ? vs : ldnt4((const uint4*)(x0 + (size_t)grow*H + lr*8));
      float s0 = 0.9f*a[0] + 0.1f*bf2f((ushort)(xv.x & 0xffff));
      float s1 = 0.9f*a[1] + 0.1f*bf2f((ushort)(xv.x >> 16));
      float s2 = 0.9f*a[2] + 0.1f*bf2f((ushort)(xv.y & 0xffff));
      float s3 = 0.9f*a[3] + 0.1f*bf2f((ushort)(xv.y >> 16));
      float s4 = 0.9f*a[4] + 0.1f*bf2f((ushort)(xv.z & 0xffff));
      float s5 = 0.9f*a[5] + 0.1f*bf2f((ushort)(xv.z >> 16));
      float s6 = 0.9f*a[6] + 0.1f*bf2f((ushort)(xv.w & 0xffff));
      float s7 = 0.9f*a[7] + 0.1f*bf2f((ushort)(xv.w >> 16));
      pk.x = (uint)f2bf(s0) | ((uint)f2bf(s1) << 16);
      pk.y = (uint)f2bf(s2) | ((uint)f2bf(s3) << 16);
      pk.z = (uint)f2bf(s4) | ((uint)f2bf(s5) << 16);
      pk.w = (uint)f2bf(s6) | ((uint)f2bf(s7) << 16);
    }
    *(uint4*)(&Sm[row*128 + ((lr ^ (row & 15))*8)]) = pk;
  }

  // ---- B fragments (W'^T slice for this wave's 32 cols) ----
  short8 bfr[2][4];
  #pragma unroll
  for (int c = 0; c < 2; ++c)
    #pragma unroll
    for (int ks = 0; ks < 4; ++ks)
      bfr[c][ks] = *(const short8*)(BT + (size_t)(w*32 + c*16 + lr)*H + ks*32 + q*8);

  __syncthreads();

  // ---- GEMM phase: 32 rows x 32 cols per wave ----
  f32x4 acc[2][2];
  #pragma unroll
  for (int rt = 0; rt < 2; ++rt){
    acc[rt][0] = (f32x4){0.f,0.f,0.f,0.f};
    acc[rt][1] = (f32x4){0.f,0.f,0.f,0.f};
  }
  #pragma unroll
  for (int rt = 0; rt < 2; ++rt){
    int row = rt*16 + lr;
    #pragma unroll
    for (int ks = 0; ks < 4; ++ks){
      short8 af = *(const short8*)(&Sm[row*128 + (((ks*4 + q) ^ (row & 15))*8)]);
      acc[rt][0] = __builtin_amdgcn_mfma_f32_16x16x32_bf16(af, bfr[0][ks], acc[rt][0], 0,0,0);
      acc[rt][1] = __builtin_amdgcn_mfma_f32_16x16x32_bf16(af, bfr[1][ks], acc[rt][1], 0,0,0);
    }
  }

  // ---- epilogue: bf16 -> contiguous permuted rows; f32 -> original rows ----
  #pragma unroll
  for (int rt = 0; rt < 2; ++rt){
    #pragma unroll
    for (int c = 0; c < 2; ++c){
      #pragma unroll
      for (int j2 = 0; j2 < 4; ++j2){
        int rowl = rt*16 + q*4 + j2;
        float v = acc[rt][c][j2];
        if (OUTF32){
          int nodeo = pm[rowl];
          if (nodeo >= 0)
            ((float*)zout)[(size_t)nodeo*H + w*32 + c*16 + lr] = v;
        } else {
          int growl = base + rowl;
          float other = __shfl(v, l ^ 1);
          if (!(lr & 1) && growl < n){
            uint pk = (uint)f2bf(v) | ((uint)f2bf(other) << 16);
            ((uint*)zout)[(size_t)growl*64 + w*16 + c*8 + (lr >> 1)] = pk;
          }
        }
      }
    }
  }
  if (STATS){
    #pragma unroll
    for (int c = 0; c < 2; ++c){
      float sv = 0.f, sq = 0.f;
      #pragma unroll
      for (int rt = 0; rt < 2; ++rt)
        #pragma unroll
        for (int j2 = 0; j2 < 4; ++j2){
          float v = acc[rt][c][j2];   // invalid rows have s=0 -> acc=0
          sv += v; sq += v*v;
        }
      sv += __shfl(sv, l ^ 16); sv += __shfl(sv, l ^ 32);
      sq += __shfl(sq, l ^ 16); sq += __shfl(sq, l ^ 32);
      if (q == 0){
        float* st = stats + (size_t)(blockIdx.x & (RSTATS-1))*256;
        atomicAdd(&st[w*32 + c*16 + lr], sv);
        atomicAdd(&st[128 + w*32 + c*16 + lr], sq);
      }
    }
  }
}

// ---------------- BN finalize: stats replicas -> scale/shift; re-zero -------

__global__ void k_bnfinal(float* __restrict__ stats, const float* __restrict__ gamma,
                          const float* __restrict__ beta, float* __restrict__ scsh,
                          float inv_n){
  int f = threadIdx.x;   // 128
  float s = 0.f, s2 = 0.f;
  for (int r = 0; r < RSTATS; ++r){
    s  += stats[r*256 + f];
    s2 += stats[r*256 + 128 + f];
    stats[r*256 + f] = 0.f;          // re-zero for next layer
    stats[r*256 + 128 + f] = 0.f;
  }
  float mu  = s * inv_n;
  float var = s2 * inv_n - mu*mu;
  float sc  = rsqrtf(var + EPS_BN) * gamma[f];
  scsh[f]       = sc;
  scsh[128 + f] = beta[f] - mu*sc;
}

// ---------------- MFMA GEMM for input layer: xw = x(perm rows) @ lin0T^T ----

__global__ __launch_bounds__(256) void k_gemm0(
    const float* __restrict__ Af, const ushort* __restrict__ BT,
    const int* __restrict__ perm, ushort* __restrict__ Cb, int n){
  const int K = 256;
  __shared__ ushort As[64*32];
  __shared__ ushort Bs[128*32];
  __shared__ int pmr[64];
  int t = threadIdx.x;
  int br = blockIdx.x * 64;
  int w = t >> 6, l = t & 63;
  int lr = l & 15, lk = l >> 4;
  int swz = (lr >> 1) & 3;
  if (t < 64) pmr[t] = (br + t < n) ? perm[br + t] : -1;
  __syncthreads();

  f32x4 acc[8];
  #pragma unroll
  for (int i = 0; i < 8; ++i) acc[i] = (f32x4){0.f,0.f,0.f,0.f};

  int sar = t >> 2;
  int sab = t & 3;
  int sa_off = sar*32 + ((sab ^ ((sar>>1)&3))*8);

  for (int k0 = 0; k0 < K; k0 += 32){
    int grow = pmr[sar];              // original row of x
    float4 v0 = make_float4(0.f,0.f,0.f,0.f), v1 = v0;
    if (grow >= 0){
      v0 = *(const float4*)(Af + (size_t)grow*K + k0 + sab*8);
      v1 = *(const float4*)(Af + (size_t)grow*K + k0 + sab*8 + 4);
    }
    ushort tmp[8] = {f2bf(v0.x),f2bf(v0.y),f2bf(v0.z),f2bf(v0.w),
                     f2bf(v1.x),f2bf(v1.y),f2bf(v1.z),f2bf(v1.w)};
    *(uint4*)(&As[sa_off]) = *(const uint4*)tmp;
    #pragma unroll
    for (int i = 0; i < 2; ++i){
      int qq = t + i*256;
      int nrow = qq >> 2, bb = qq & 3;
      uint4 v = *(const uint4*)(BT + (size_t)nrow*K + k0 + bb*8);
      *(uint4*)(&Bs[nrow*32 + ((bb ^ ((nrow>>1)&3))*8)]) = v;
    }
    __syncthreads();
    short8 af = *(const short8*)(&As[(w*16+lr)*32 + ((lk ^ swz)*8)]);
    #pragma unroll
    for (int tn = 0; tn < 8; ++tn){
      short8 bfv = *(const short8*)(&Bs[(tn*16+lr)*32 + ((lk ^ swz)*8)]);
      acc[tn] = __builtin_amdgcn_mfma_f32_16x16x32_bf16(af, bfv, acc[tn], 0, 0, 0);
    }
    __syncthreads();
  }
  int orow = br + w*16 + lk*4;        // permuted layout, contiguous
  #pragma unroll
  for (int tn = 0; tn < 8; ++tn){
    #pragma unroll
    for (int j = 0; j < 4; ++j){
      float mine  = acc[tn][j];
      float other = __shfl(mine, l ^ 1);
      if (!(l & 1) && (orow + j) < n){
        uint pk = (uint)f2bf(mine) | ((uint)f2bf(other) << 16);
        ((uint*)Cb)[(size_t)(orow+j)*64 + tn*8 + (lr >> 1)] = pk;
      }
    }
  }
}

// ---------------- launch ----------------

extern "C" void kernel_launch(void* const* d_in, const int* in_sizes, int n_in,
                              void* d_out, int out_size, void* d_ws, size_t ws_size,
                              hipStream_t stream){
  const float* x        = (const float*)d_in[0];
  const int*   ei       = (const int*)  d_in[1];
  const float* lin0_w   = (const float*)d_in[2];
  const float* lin0_b   = (const float*)d_in[3];
  const float* conv_w   = (const float*)d_in[4];
  const float* bn_gamma = (const float*)d_in[5];
  const float* bn_beta  = (const float*)d_in[6];
  float* out = (float*)d_out;

  int N = in_sizes[0] / 256;
  int E = in_sizes[1] / 2;
  const int* row = ei;
  const int* col = ei + E;

  char* ws = (char*)d_ws;
  size_t p = 0;
  auto alloc = [&](size_t bytes)->char*{
    char* r = ws + p; p = (p + bytes + 255) & ~(size_t)255; return r;
  };
  int*    cnt    = (int*)   alloc((size_t)N*4);
  int*    off    = (int*)   alloc((size_t)(N+1)*4);
  int*    cursor = (int*)   alloc((size_t)N*4);
  float*  dinv   = (float*) alloc((size_t)N*4);
  int*    bsum   = (int*)   alloc(512*4);
  int*    dh     = (int*)   alloc(256*4);
  int*    perm   = (int*)   alloc((size_t)N*4);
  int*    iperm  = (int*)   alloc((size_t)N*4);
  uint2*  edge   = (uint2*) alloc((size_t)E*8);
  ushort* zb     = (ushort*)alloc((size_t)N*H*2);
  ushort* sb     = (ushort*)alloc((size_t)N*H*2);   // xw, then ping-pong z
  ushort* x0b    = (ushort*)alloc((size_t)N*H*2);
  ushort* lin0T  = (ushort*)alloc(128*256*2);
  ushort* WpT    = (ushort*)alloc(4*128*128*2);
  float*  stats  = (float*) alloc(RSTATS*256*4);
  float*  scsh   = (float*) alloc(2*128*4);

  float betas[4];
  for (int i = 0; i < 4; ++i) betas[i] = logf(0.5f/(float)(i+1) + 1.0f);
  float inv_n = 1.0f/(float)N;

  // ---- CSR build + degree-sort perm (descending; LDS-aggregated) ----
  hipMemsetAsync(cnt, 0, (size_t)N*4, stream);
  hipMemsetAsync(dh, 0, 256*4, stream);
  k_count<<<(E+255)/256, 256, 0, stream>>>(col, E, cnt);
  int nb1k = (N + 1023)/1024;
  k_dhist<<<nb1k, 1024, 0, stream>>>(cnt, dh, N);
  k_dscan<<<1, 256, 0, stream>>>(dh);
  k_dperm<<<nb1k, 1024, 0, stream>>>(cnt, dh, perm, iperm, N);
  k_scan1<<<nb1k, 1024, 0, stream>>>(cnt, off, bsum, dinv, N);
  k_scan2<<<1, 64, 0, stream>>>(bsum, nb1k);
  k_scan3<<<(N+255)/256, 256, 0, stream>>>(off, cursor, bsum, N, E);
  k_fill <<<(E+255)/256, 256, 0, stream>>>(row, col, E, dinv, iperm, cursor, edge);

  k_prepw<<<(128*256 + 4*128*128 + 255)/256, 256, 0, stream>>>(
      lin0_w, conv_w, lin0T, WpT, betas[0], betas[1], betas[2], betas[3]);

  int gemm_blocks = (N + 63)/64;
  int lay_blocks  = (N + 31)/32;
  int prop_blocks = (N + 15)/16;      // 16 quads (nodes) per 256-thread block

  // ---- input layer: xw = x @ lin0 (permuted rows); x0 = prop(xw)+b ----
  k_gemm0<<<gemm_blocks, 256, 0, stream>>>(x, lin0T, perm, sb, N);
  k_prop0<<<prop_blocks, 256, 0, stream>>>(sb, off, edge, dinv, lin0_b, perm, x0b, N);

  hipMemsetAsync(stats, 0, RSTATS*256*4, stream);   // once; k_bnfinal re-zeroes

  // ---- layer 0: zin=x0b (raw, == x0) -> zout=sb (raw z1), stats ----
  k_layer<false,true,false,true><<<lay_blocks, 256, 0, stream>>>(
      x0b, x0b, off, edge, dinv, WpT + 0*128*128, perm, nullptr, sb, stats, N);
  k_bnfinal<<<1, 128, 0, stream>>>(stats, bn_gamma + 0*H, bn_beta + 0*H, scsh, inv_n);

  // ---- layer 1: zin=sb (raw, BN in gather) -> zout=zb (raw z2), stats ----
  k_layer<true,true,false,false><<<lay_blocks, 256, 0, stream>>>(
      sb, x0b, off, edge, dinv, WpT + 1*128*128, perm, scsh, zb, stats, N);
  k_bnfinal<<<1, 128, 0, stream>>>(stats, bn_gamma + 1*H, bn_beta + 1*H, scsh, inv_n);

  // ---- layer 2: zin=zb (raw, BN in gather) -> zout=sb (raw z3), stats ----
  k_layer<true,true,false,false><<<lay_blocks, 256, 0, stream>>>(
      zb, x0b, off, edge, dinv, WpT + 2*128*128, perm, scsh, sb, stats, N);
  k_bnfinal<<<1, 128, 0, stream>>>(stats, bn_gamma + 2*H, bn_beta + 2*H, scsh, inv_n);

  // ---- layer 3: zin=sb (raw, BN in gather) -> out (f32, original rows) ----
  k_layer<true,false,true,false><<<lay_blocks, 256, 0, stream>>>(
      sb, x0b, off, edge, dinv, WpT + 3*128*128, perm, scsh, out, nullptr, N);
}

// Round 21
// 576.333 us; speedup vs baseline: 1.1416x; 1.1416x over previous
//
#include <hip/hip_runtime.h>
#include <hip/hip_bf16.h>
#include <math.h>

#define H 128
#define EPS_BN 1e-5f
#define RSTATS 16

typedef __attribute__((ext_vector_type(8))) short short8;
typedef __attribute__((ext_vector_type(4))) float f32x4;
typedef unsigned long long ull;

__device__ __forceinline__ float bf2f(ushort u){
  union { float f; uint v; } x; x.v = ((uint)u) << 16; return x.f;
}
__device__ __forceinline__ ushort f2bf(float f){
  union { float f; uint v; } x; x.f = f;
  uint v = x.v;
  uint r = v + 0x7fff + ((v >> 16) & 1);   // RNE
  return (ushort)(r >> 16);
}

__device__ __forceinline__ void acc8(float* a, uint4 v, float wt){
  a[0] += wt*bf2f((ushort)(v.x & 0xffff)); a[1] += wt*bf2f((ushort)(v.x >> 16));
  a[2] += wt*bf2f((ushort)(v.y & 0xffff)); a[3] += wt*bf2f((ushort)(v.y >> 16));
  a[4] += wt*bf2f((ushort)(v.z & 0xffff)); a[5] += wt*bf2f((ushort)(v.z >> 16));
  a[6] += wt*bf2f((ushort)(v.w & 0xffff)); a[7] += wt*bf2f((ushort)(v.w >> 16));
}
// BN+ReLU applied to the loaded row before accumulation
__device__ __forceinline__ void acc8bn(float* a, uint4 v, float wt,
                                       const float* sc, const float* sh){
  float z[8] = { bf2f((ushort)(v.x & 0xffff)), bf2f((ushort)(v.x >> 16)),
                 bf2f((ushort)(v.y & 0xffff)), bf2f((ushort)(v.y >> 16)),
                 bf2f((ushort)(v.z & 0xffff)), bf2f((ushort)(v.z >> 16)),
                 bf2f((ushort)(v.w & 0xffff)), bf2f((ushort)(v.w >> 16)) };
  #pragma unroll
  for (int j = 0; j < 8; ++j){
    float y = fmaxf(fmaf(z[j], sc[j], sh[j]), 0.f);
    a[j] = fmaf(wt, y, a[j]);
  }
}

// ---------------- CSR build (simple single-pass) ----------------

__global__ void k_count(const int* __restrict__ col, int E, int* __restrict__ cnt){
  int i = blockIdx.x*blockDim.x + threadIdx.x;
  if (i < E){
    int c = __builtin_nontemporal_load(col + i);
    atomicAdd(&cnt[c], 1);
  }
}

__global__ void k_scan1(const int* __restrict__ cnt, int* __restrict__ off,
                        int* __restrict__ bsum, float* __restrict__ dinv, int n){
  __shared__ int s[1024];
  int t = threadIdx.x;
  int i = blockIdx.x*1024 + t;
  int v = (i < n) ? cnt[i] : 0;
  if (i < n) dinv[i] = rsqrtf((float)v + 1.0f);   // +1 self-loop
  s[t] = v; __syncthreads();
  for (int d = 1; d < 1024; d <<= 1){
    int x = (t >= d) ? s[t-d] : 0;
    __syncthreads();
    s[t] += x;
    __syncthreads();
  }
  if (i < n) off[i] = s[t] - v;
  if (t == 1023) bsum[blockIdx.x] = s[1023];
}

__global__ void k_scan2(int* bsum, int nb){
  int l = threadIdx.x;           // 64 threads, 1 block
  int carry = 0;
  for (int b0 = 0; b0 < nb; b0 += 64){
    int i = b0 + l;
    int orig = (i < nb) ? bsum[i] : 0;
    int v = orig;
    #pragma unroll
    for (int d = 1; d < 64; d <<= 1){
      int x = __shfl_up(v, d);
      if (l >= d) v += x;
    }
    if (i < nb) bsum[i] = carry + v - orig;   // exclusive
    carry += __shfl(v, 63);
  }
}

__global__ void k_scan3(int* __restrict__ off, int* __restrict__ cursor,
                        const int* __restrict__ bsum, int n, int Etot){
  int i = blockIdx.x*blockDim.x + threadIdx.x;
  if (i < n){ int o = off[i] + bsum[i >> 10]; off[i] = o; cursor[i] = o; }
  if (i == 0) off[n] = Etot;
}

// edge record = {permuted source row, weight}; NONTEMPORAL store (no-allocate)
__global__ void k_fill(const int* __restrict__ row, const int* __restrict__ col, int E,
                       const float* __restrict__ dinv, const int* __restrict__ iperm,
                       int* __restrict__ cursor, uint2* __restrict__ edge){
  int i = blockIdx.x*blockDim.x + threadIdx.x;
  if (i < E){
    int c = __builtin_nontemporal_load(col + i);
    int r = __builtin_nontemporal_load(row + i);
    int p = atomicAdd(&cursor[c], 1);
    ull v = ((ull)__float_as_uint(dinv[r]*dinv[c]) << 32) | (ull)(uint)iperm[r];
    __builtin_nontemporal_store(v, (ull*)(edge + p));
  }
}

// -------- degree-sort permutation (DESCENDING): LDS-aggregated counting sort --

__global__ __launch_bounds__(1024) void k_dhist(
    const int* __restrict__ cnt, int* __restrict__ dh, int n){
  __shared__ int lh[256];
  int t = threadIdx.x;
  if (t < 256) lh[t] = 0;
  __syncthreads();
  int i = blockIdx.x*1024 + t;
  if (i < n){
    int d = cnt[i]; if (d > 255) d = 255;
    atomicAdd(&lh[d], 1);
  }
  __syncthreads();
  if (t < 256 && lh[t]) atomicAdd(&dh[t], lh[t]);
}

__global__ void k_dscan(int* __restrict__ dh){   // 1 block, 256 thr; DESC offsets
  __shared__ int s[256];
  int t = threadIdx.x;
  int v = dh[255 - t];              // reversed order
  s[t] = v; __syncthreads();
  for (int d = 1; d < 256; d <<= 1){
    int x = (t >= d) ? s[t-d] : 0;
    __syncthreads();
    s[t] += x;
    __syncthreads();
  }
  dh[255 - t] = s[t] - v;   // bin d offset = count of nodes with degree > d
}

__global__ __launch_bounds__(1024) void k_dperm(
    const int* __restrict__ cnt, int* __restrict__ dh,
    int* __restrict__ perm, int* __restrict__ iperm, int n){
  __shared__ int lh[256];
  __shared__ int lbase[256];
  int t = threadIdx.x;
  if (t < 256) lh[t] = 0;
  __syncthreads();
  int i = blockIdx.x*1024 + t;
  int d = 0, li = 0;
  if (i < n){
    d = cnt[i]; if (d > 255) d = 255;
    li = atomicAdd(&lh[d], 1);
  }
  __syncthreads();
  if (t < 256){
    int c = lh[t];
    lbase[t] = c ? atomicAdd(&dh[t], c) : 0;
  }
  __syncthreads();
  if (i < n){
    int pos = lbase[d] + li;
    perm[pos] = i;
    iperm[i] = pos;
  }
}

// ---------------- weight prep: bf16, transposed, beta-folded ----------------

__global__ void k_prepw(const float* __restrict__ lin0_w, const float* __restrict__ conv_w,
                        ushort* __restrict__ lin0T, ushort* __restrict__ WpT,
                        float b0, float b1, float b2, float b3){
  int i = blockIdx.x*blockDim.x + threadIdx.x;
  if (i < 128*256){
    int nn = i >> 8, k = i & 255;
    lin0T[i] = f2bf(lin0_w[k*128 + nn]);
  } else if (i < 128*256 + 4*128*128){
    int j = i - 128*256;
    int ll = j >> 14, rc = j & 16383;
    int nn = rc >> 7, k = rc & 127;
    float beta = (ll==0)?b0:(ll==1)?b1:(ll==2)?b2:b3;
    float v = beta * conv_w[ll*16384 + k*128 + nn];
    if (k == nn) v += 1.0f - beta;
    WpT[j] = f2bf(v);
  }
}

// ---------------- gather cores: one quad (16 lanes) per node ----------------
// 8-wide unroll: 8 row-reads in flight per quad (deg~17 -> 2 main-loop trips).

__device__ __forceinline__ void gather_edges(
    float* a, const ushort* __restrict__ zin, const uint2* __restrict__ edge,
    int e0, int e1, int lr){
  int e = e0;
  for (; e + 7 < e1; e += 8){
    uint2 er0 = edge[e],   er1 = edge[e+1], er2 = edge[e+2], er3 = edge[e+3];
    uint2 er4 = edge[e+4], er5 = edge[e+5], er6 = edge[e+6], er7 = edge[e+7];
    uint4 v0 = *(const uint4*)(zin + (size_t)er0.x*H + lr*8);
    uint4 v1 = *(const uint4*)(zin + (size_t)er1.x*H + lr*8);
    uint4 v2 = *(const uint4*)(zin + (size_t)er2.x*H + lr*8);
    uint4 v3 = *(const uint4*)(zin + (size_t)er3.x*H + lr*8);
    uint4 v4 = *(const uint4*)(zin + (size_t)er4.x*H + lr*8);
    uint4 v5 = *(const uint4*)(zin + (size_t)er5.x*H + lr*8);
    uint4 v6 = *(const uint4*)(zin + (size_t)er6.x*H + lr*8);
    uint4 v7 = *(const uint4*)(zin + (size_t)er7.x*H + lr*8);
    acc8(a, v0, __uint_as_float(er0.y));
    acc8(a, v1, __uint_as_float(er1.y));
    acc8(a, v2, __uint_as_float(er2.y));
    acc8(a, v3, __uint_as_float(er3.y));
    acc8(a, v4, __uint_as_float(er4.y));
    acc8(a, v5, __uint_as_float(er5.y));
    acc8(a, v6, __uint_as_float(er6.y));
    acc8(a, v7, __uint_as_float(er7.y));
  }
  for (; e + 3 < e1; e += 4){
    uint2 er0 = edge[e], er1 = edge[e+1], er2 = edge[e+2], er3 = edge[e+3];
    uint4 v0 = *(const uint4*)(zin + (size_t)er0.x*H + lr*8);
    uint4 v1 = *(const uint4*)(zin + (size_t)er1.x*H + lr*8);
    uint4 v2 = *(const uint4*)(zin + (size_t)er2.x*H + lr*8);
    uint4 v3 = *(const uint4*)(zin + (size_t)er3.x*H + lr*8);
    acc8(a, v0, __uint_as_float(er0.y));
    acc8(a, v1, __uint_as_float(er1.y));
    acc8(a, v2, __uint_as_float(er2.y));
    acc8(a, v3, __uint_as_float(er3.y));
  }
  for (; e < e1; ++e){
    uint2 er = edge[e];
    uint4 v = *(const uint4*)(zin + (size_t)er.x*H + lr*8);
    acc8(a, v, __uint_as_float(er.y));
  }
}

__device__ __forceinline__ void gather_edges_bn(
    float* a, const ushort* __restrict__ zin, const uint2* __restrict__ edge,
    int e0, int e1, int lr, const float* sc, const float* sh){
  int e = e0;
  for (; e + 7 < e1; e += 8){
    uint2 er0 = edge[e],   er1 = edge[e+1], er2 = edge[e+2], er3 = edge[e+3];
    uint2 er4 = edge[e+4], er5 = edge[e+5], er6 = edge[e+6], er7 = edge[e+7];
    uint4 v0 = *(const uint4*)(zin + (size_t)er0.x*H + lr*8);
    uint4 v1 = *(const uint4*)(zin + (size_t)er1.x*H + lr*8);
    uint4 v2 = *(const uint4*)(zin + (size_t)er2.x*H + lr*8);
    uint4 v3 = *(const uint4*)(zin + (size_t)er3.x*H + lr*8);
    uint4 v4 = *(const uint4*)(zin + (size_t)er4.x*H + lr*8);
    uint4 v5 = *(const uint4*)(zin + (size_t)er5.x*H + lr*8);
    uint4 v6 = *(const uint4*)(zin + (size_t)er6.x*H + lr*8);
    uint4 v7 = *(const uint4*)(zin + (size_t)er7.x*H + lr*8);
    acc8bn(a, v0, __uint_as_float(er0.y), sc, sh);
    acc8bn(a, v1, __uint_as_float(er1.y), sc, sh);
    acc8bn(a, v2, __uint_as_float(er2.y), sc, sh);
    acc8bn(a, v3, __uint_as_float(er3.y), sc, sh);
    acc8bn(a, v4, __uint_as_float(er4.y), sc, sh);
    acc8bn(a, v5, __uint_as_float(er5.y), sc, sh);
    acc8bn(a, v6, __uint_as_float(er6.y), sc, sh);
    acc8bn(a, v7, __uint_as_float(er7.y), sc, sh);
  }
  for (; e + 3 < e1; e += 4){
    uint2 er0 = edge[e], er1 = edge[e+1], er2 = edge[e+2], er3 = edge[e+3];
    uint4 v0 = *(const uint4*)(zin + (size_t)er0.x*H + lr*8);
    uint4 v1 = *(const uint4*)(zin + (size_t)er1.x*H + lr*8);
    uint4 v2 = *(const uint4*)(zin + (size_t)er2.x*H + lr*8);
    uint4 v3 = *(const uint4*)(zin + (size_t)er3.x*H + lr*8);
    acc8bn(a, v0, __uint_as_float(er0.y), sc, sh);
    acc8bn(a, v1, __uint_as_float(er1.y), sc, sh);
    acc8bn(a, v2, __uint_as_float(er2.y), sc, sh);
    acc8bn(a, v3, __uint_as_float(er3.y), sc, sh);
  }
  for (; e < e1; ++e){
    uint2 er = edge[e];
    uint4 v = *(const uint4*)(zin + (size_t)er.x*H + lr*8);
    acc8bn(a, v, __uint_as_float(er.y), sc, sh);
  }
}

// ---------------- input-layer prop: x0 = agg(xw)+b ; permuted layout --------

__global__ __launch_bounds__(256) void k_prop0(
    const ushort* __restrict__ h, const int* __restrict__ off,
    const uint2* __restrict__ edge, const float* __restrict__ dinv,
    const float* __restrict__ bias, const int* __restrict__ perm,
    ushort* __restrict__ x0, int n){
  int pq = (blockIdx.x*blockDim.x + threadIdx.x) >> 4;   // permuted row
  if (pq >= n) return;
  int gq = perm[pq];                 // original node (off/dinv)
  int lr = threadIdx.x & 15;
  float a[8];
  #pragma unroll
  for (int j = 0; j < 8; ++j) a[j] = 0.f;
  float wc = dinv[gq]; wc *= wc;
  uint4 vs = *(const uint4*)(h + (size_t)pq*H + lr*8);   // self: permuted row
  gather_edges(a, h, edge, off[gq], off[gq+1], lr);
  acc8(a, vs, wc);
  float4 b0 = *(const float4*)(bias + lr*8);
  float4 b1 = *(const float4*)(bias + lr*8 + 4);
  uint4 pk;
  pk.x = (uint)f2bf(a[0]+b0.x) | ((uint)f2bf(a[1]+b0.y) << 16);
  pk.y = (uint)f2bf(a[2]+b0.z) | ((uint)f2bf(a[3]+b0.w) << 16);
  pk.z = (uint)f2bf(a[4]+b1.x) | ((uint)f2bf(a[5]+b1.y) << 16);
  pk.w = (uint)f2bf(a[6]+b1.z) | ((uint)f2bf(a[7]+b1.w) << 16);
  *(uint4*)(x0 + (size_t)pq*H + lr*8) = pk;              // contiguous write
}

// ---------------- fused layer: [BN+ReLU ->] prop -> MFMA GEMM -> z (+stats) --

template<bool BNIN, bool STATS, bool OUTF32, bool SAMEX0>
__global__ __launch_bounds__(256) void k_layer(
    const ushort* __restrict__ zin, const ushort* __restrict__ x0,
    const int* __restrict__ off, const uint2* __restrict__ edge,
    const float* __restrict__ dinv, const ushort* __restrict__ BT,
    const int* __restrict__ perm, const float* __restrict__ scsh,
    void* __restrict__ zout, float* __restrict__ stats, int n)
{
  __shared__ ushort Sm[32*128];   // swizzled s tile: row*128 + ((blk16^(row&15))*8)
  __shared__ int pm[32];
  int t = threadIdx.x;
  int w = t >> 6, l = t & 63;
  int lr = l & 15, q = l >> 4;
  int base = blockIdx.x * 32;
  if (t < 32) pm[t] = (base + t < n) ? perm[base + t] : -1;

  float sc[8], sh[8];
  if (BNIN){
    #pragma unroll
    for (int j = 0; j < 8; ++j){
      sc[j] = scsh[lr*8 + j];
      sh[j] = scsh[128 + lr*8 + j];
    }
  }
  __syncthreads();

  // ---- prop phase: quad-per-node, 2 nodes per quad ----
  #pragma unroll
  for (int g2 = 0; g2 < 2; ++g2){
    int row  = w*8 + g2*4 + q;
    int node = pm[row];             // original id (off/dinv only)
    int grow = base + row;          // permuted row (addresses)
    float a[8];
    #pragma unroll
    for (int j = 0; j < 8; ++j) a[j] = 0.f;
    uint4 pk = make_uint4(0u,0u,0u,0u);
    if (node >= 0){
      float wc = dinv[node]; wc *= wc;
      uint4 vs = *(const uint4*)(zin + (size_t)grow*H + lr*8);
      if (BNIN){
        gather_edges_bn(a, zin, edge, off[node], off[node+1], lr, sc, sh);
        acc8bn(a, vs, wc, sc, sh);
      } else {
        gather_edges(a, zin, edge, off[node], off[node+1], lr);
        acc8(a, vs, wc);
      }
      uint4 xv = SAMEX0 ? vs : *(const uint4*)(x0 + (size_t)grow*H + lr*8);
      float s0 = 0.9f*a[0] + 0.1f*bf2f((ushort)(xv.x & 0xffff));
      float s1 = 0.9f*a[1] + 0.1f*bf2f((ushort)(xv.x >> 16));
      float s2 = 0.9f*a[2] + 0.1f*bf2f((ushort)(xv.y & 0xffff));
      float s3 = 0.9f*a[3] + 0.1f*bf2f((ushort)(xv.y >> 16));
      float s4 = 0.9f*a[4] + 0.1f*bf2f((ushort)(xv.z & 0xffff));
      float s5 = 0.9f*a[5] + 0.1f*bf2f((ushort)(xv.z >> 16));
      float s6 = 0.9f*a[6] + 0.1f*bf2f((ushort)(xv.w & 0xffff));
      float s7 = 0.9f*a[7] + 0.1f*bf2f((ushort)(xv.w >> 16));
      pk.x = (uint)f2bf(s0) | ((uint)f2bf(s1) << 16);
      pk.y = (uint)f2bf(s2) | ((uint)f2bf(s3) << 16);
      pk.z = (uint)f2bf(s4) | ((uint)f2bf(s5) << 16);
      pk.w = (uint)f2bf(s6) | ((uint)f2bf(s7) << 16);
    }
    *(uint4*)(&Sm[row*128 + ((lr ^ (row & 15))*8)]) = pk;
  }

  // ---- B fragments (W'^T slice for this wave's 32 cols) ----
  short8 bfr[2][4];
  #pragma unroll
  for (int c = 0; c < 2; ++c)
    #pragma unroll
    for (int ks = 0; ks < 4; ++ks)
      bfr[c][ks] = *(const short8*)(BT + (size_t)(w*32 + c*16 + lr)*H + ks*32 + q*8);

  __syncthreads();

  // ---- GEMM phase: 32 rows x 32 cols per wave ----
  f32x4 acc[2][2];
  #pragma unroll
  for (int rt = 0; rt < 2; ++rt){
    acc[rt][0] = (f32x4){0.f,0.f,0.f,0.f};
    acc[rt][1] = (f32x4){0.f,0.f,0.f,0.f};
  }
  #pragma unroll
  for (int rt = 0; rt < 2; ++rt){
    int row = rt*16 + lr;
    #pragma unroll
    for (int ks = 0; ks < 4; ++ks){
      short8 af = *(const short8*)(&Sm[row*128 + (((ks*4 + q) ^ (row & 15))*8)]);
      acc[rt][0] = __builtin_amdgcn_mfma_f32_16x16x32_bf16(af, bfr[0][ks], acc[rt][0], 0,0,0);
      acc[rt][1] = __builtin_amdgcn_mfma_f32_16x16x32_bf16(af, bfr[1][ks], acc[rt][1], 0,0,0);
    }
  }

  // ---- epilogue: bf16 -> contiguous permuted rows; f32 -> original rows ----
  #pragma unroll
  for (int rt = 0; rt < 2; ++rt){
    #pragma unroll
    for (int c = 0; c < 2; ++c){
      #pragma unroll
      for (int j2 = 0; j2 < 4; ++j2){
        int rowl = rt*16 + q*4 + j2;
        float v = acc[rt][c][j2];
        if (OUTF32){
          int nodeo = pm[rowl];
          if (nodeo >= 0)
            ((float*)zout)[(size_t)nodeo*H + w*32 + c*16 + lr] = v;
        } else {
          int growl = base + rowl;
          float other = __shfl(v, l ^ 1);
          if (!(lr & 1) && growl < n){
            uint pk = (uint)f2bf(v) | ((uint)f2bf(other) << 16);
            ((uint*)zout)[(size_t)growl*64 + w*16 + c*8 + (lr >> 1)] = pk;
          }
        }
      }
    }
  }
  if (STATS){
    #pragma unroll
    for (int c = 0; c < 2; ++c){
      float sv = 0.f, sq = 0.f;
      #pragma unroll
      for (int rt = 0; rt < 2; ++rt)
        #pragma unroll
        for (int j2 = 0; j2 < 4; ++j2){
          float v = acc[rt][c][j2];   // invalid rows have s=0 -> acc=0
          sv += v; sq += v*v;
        }
      sv += __shfl(sv, l ^ 16); sv += __shfl(sv, l ^ 32);
      sq += __shfl(sq, l ^ 16); sq += __shfl(sq, l ^ 32);
      if (q == 0){
        float* st = stats + (size_t)(blockIdx.x & (RSTATS-1))*256;
        atomicAdd(&st[w*32 + c*16 + lr], sv);
        atomicAdd(&st[128 + w*32 + c*16 + lr], sq);
      }
    }
  }
}

// ---------------- BN finalize: stats replicas -> scale/shift; re-zero -------

__global__ void k_bnfinal(float* __restrict__ stats, const float* __restrict__ gamma,
                          const float* __restrict__ beta, float* __restrict__ scsh,
                          float inv_n){
  int f = threadIdx.x;   // 128
  float s = 0.f, s2 = 0.f;
  for (int r = 0; r < RSTATS; ++r){
    s  += stats[r*256 + f];
    s2 += stats[r*256 + 128 + f];
    stats[r*256 + f] = 0.f;          // re-zero for next layer
    stats[r*256 + 128 + f] = 0.f;
  }
  float mu  = s * inv_n;
  float var = s2 * inv_n - mu*mu;
  float sc  = rsqrtf(var + EPS_BN) * gamma[f];
  scsh[f]       = sc;
  scsh[128 + f] = beta[f] - mu*sc;
}

// ---------------- MFMA GEMM for input layer: xw = x(perm rows) @ lin0T^T ----

__global__ __launch_bounds__(256) void k_gemm0(
    const float* __restrict__ Af, const ushort* __restrict__ BT,
    const int* __restrict__ perm, ushort* __restrict__ Cb, int n){
  const int K = 256;
  __shared__ ushort As[64*32];
  __shared__ ushort Bs[128*32];
  __shared__ int pmr[64];
  int t = threadIdx.x;
  int br = blockIdx.x * 64;
  int w = t >> 6, l = t & 63;
  int lr = l & 15, lk = l >> 4;
  int swz = (lr >> 1) & 3;
  if (t < 64) pmr[t] = (br + t < n) ? perm[br + t] : -1;
  __syncthreads();

  f32x4 acc[8];
  #pragma unroll
  for (int i = 0; i < 8; ++i) acc[i] = (f32x4){0.f,0.f,0.f,0.f};

  int sar = t >> 2;
  int sab = t & 3;
  int sa_off = sar*32 + ((sab ^ ((sar>>1)&3))*8);

  for (int k0 = 0; k0 < K; k0 += 32){
    int grow = pmr[sar];              // original row of x
    float4 v0 = make_float4(0.f,0.f,0.f,0.f), v1 = v0;
    if (grow >= 0){
      v0 = *(const float4*)(Af + (size_t)grow*K + k0 + sab*8);
      v1 = *(const float4*)(Af + (size_t)grow*K + k0 + sab*8 + 4);
    }
    ushort tmp[8] = {f2bf(v0.x),f2bf(v0.y),f2bf(v0.z),f2bf(v0.w),
                     f2bf(v1.x),f2bf(v1.y),f2bf(v1.z),f2bf(v1.w)};
    *(uint4*)(&As[sa_off]) = *(const uint4*)tmp;
    #pragma unroll
    for (int i = 0; i < 2; ++i){
      int qq = t + i*256;
      int nrow = qq >> 2, bb = qq & 3;
      uint4 v = *(const uint4*)(BT + (size_t)nrow*K + k0 + bb*8);
      *(uint4*)(&Bs[nrow*32 + ((bb ^ ((nrow>>1)&3))*8)]) = v;
    }
    __syncthreads();
    short8 af = *(const short8*)(&As[(w*16+lr)*32 + ((lk ^ swz)*8)]);
    #pragma unroll
    for (int tn = 0; tn < 8; ++tn){
      short8 bfv = *(const short8*)(&Bs[(tn*16+lr)*32 + ((lk ^ swz)*8)]);
      acc[tn] = __builtin_amdgcn_mfma_f32_16x16x32_bf16(af, bfv, acc[tn], 0, 0, 0);
    }
    __syncthreads();
  }
  int orow = br + w*16 + lk*4;        // permuted layout, contiguous
  #pragma unroll
  for (int tn = 0; tn < 8; ++tn){
    #pragma unroll
    for (int j = 0; j < 4; ++j){
      float mine  = acc[tn][j];
      float other = __shfl(mine, l ^ 1);
      if (!(l & 1) && (orow + j) < n){
        uint pk = (uint)f2bf(mine) | ((uint)f2bf(other) << 16);
        ((uint*)Cb)[(size_t)(orow+j)*64 + tn*8 + (lr >> 1)] = pk;
      }
    }
  }
}

// ---------------- launch ----------------

extern "C" void kernel_launch(void* const* d_in, const int* in_sizes, int n_in,
                              void* d_out, int out_size, void* d_ws, size_t ws_size,
                              hipStream_t stream){
  const float* x        = (const float*)d_in[0];
  const int*   ei       = (const int*)  d_in[1];
  const float* lin0_w   = (const float*)d_in[2];
  const float* lin0_b   = (const float*)d_in[3];
  const float* conv_w   = (const float*)d_in[4];
  const float* bn_gamma = (const float*)d_in[5];
  const float* bn_beta  = (const float*)d_in[6];
  float* out = (float*)d_out;

  int N = in_sizes[0] / 256;
  int E = in_sizes[1] / 2;
  const int* row = ei;
  const int* col = ei + E;

  char* ws = (char*)d_ws;
  size_t p = 0;
  auto alloc = [&](size_t bytes)->char*{
    char* r = ws + p; p = (p + bytes + 255) & ~(size_t)255; return r;
  };
  int*    cnt    = (int*)   alloc((size_t)N*4);
  int*    off    = (int*)   alloc((size_t)(N+1)*4);
  int*    cursor = (int*)   alloc((size_t)N*4);
  float*  dinv   = (float*) alloc((size_t)N*4);
  int*    bsum   = (int*)   alloc(512*4);
  int*    dh     = (int*)   alloc(256*4);
  int*    perm   = (int*)   alloc((size_t)N*4);
  int*    iperm  = (int*)   alloc((size_t)N*4);
  uint2*  edge   = (uint2*) alloc((size_t)E*8);
  ushort* zb     = (ushort*)alloc((size_t)N*H*2);
  ushort* sb     = (ushort*)alloc((size_t)N*H*2);   // xw, then ping-pong z
  ushort* x0b    = (ushort*)alloc((size_t)N*H*2);
  ushort* lin0T  = (ushort*)alloc(128*256*2);
  ushort* WpT    = (ushort*)alloc(4*128*128*2);
  float*  stats  = (float*) alloc(RSTATS*256*4);
  float*  scsh   = (float*) alloc(2*128*4);

  float betas[4];
  for (int i = 0; i < 4; ++i) betas[i] = logf(0.5f/(float)(i+1) + 1.0f);
  float inv_n = 1.0f/(float)N;

  // ---- CSR build + degree-sort perm (descending; LDS-aggregated) ----
  hipMemsetAsync(cnt, 0, (size_t)N*4, stream);
  hipMemsetAsync(dh, 0, 256*4, stream);
  k_count<<<(E+255)/256, 256, 0, stream>>>(col, E, cnt);
  int nb1k = (N + 1023)/1024;
  k_dhist<<<nb1k, 1024, 0, stream>>>(cnt, dh, N);
  k_dscan<<<1, 256, 0, stream>>>(dh);
  k_dperm<<<nb1k, 1024, 0, stream>>>(cnt, dh, perm, iperm, N);
  k_scan1<<<nb1k, 1024, 0, stream>>>(cnt, off, bsum, dinv, N);
  k_scan2<<<1, 64, 0, stream>>>(bsum, nb1k);
  k_scan3<<<(N+255)/256, 256, 0, stream>>>(off, cursor, bsum, N, E);
  k_fill <<<(E+255)/256, 256, 0, stream>>>(row, col, E, dinv, iperm, cursor, edge);

  k_prepw<<<(128*256 + 4*128*128 + 255)/256, 256, 0, stream>>>(
      lin0_w, conv_w, lin0T, WpT, betas[0], betas[1], betas[2], betas[3]);

  int gemm_blocks = (N + 63)/64;
  int lay_blocks  = (N + 31)/32;
  int prop_blocks = (N + 15)/16;      // 16 quads (nodes) per 256-thread block

  // ---- input layer: xw = x @ lin0 (permuted rows); x0 = prop(xw)+b ----
  k_gemm0<<<gemm_blocks, 256, 0, stream>>>(x, lin0T, perm, sb, N);
  k_prop0<<<prop_blocks, 256, 0, stream>>>(sb, off, edge, dinv, lin0_b, perm, x0b, N);

  hipMemsetAsync(stats, 0, RSTATS*256*4, stream);   // once; k_bnfinal re-zeroes

  // ---- layer 0: zin=x0b (raw, == x0) -> zout=sb (raw z1), stats ----
  k_layer<false,true,false,true><<<lay_blocks, 256, 0, stream>>>(
      x0b, x0b, off, edge, dinv, WpT + 0*128*128, perm, nullptr, sb, stats, N);
  k_bnfinal<<<1, 128, 0, stream>>>(stats, bn_gamma + 0*H, bn_beta + 0*H, scsh, inv_n);

  // ---- layer 1: zin=sb (raw, BN in gather) -> zout=zb (raw z2), stats ----
  k_layer<true,true,false,false><<<lay_blocks, 256, 0, stream>>>(
      sb, x0b, off, edge, dinv, WpT + 1*128*128, perm, scsh, zb, stats, N);
  k_bnfinal<<<1, 128, 0, stream>>>(stats, bn_gamma + 1*H, bn_beta + 1*H, scsh, inv_n);

  // ---- layer 2: zin=zb (raw, BN in gather) -> zout=sb (raw z3), stats ----
  k_layer<true,true,false,false><<<lay_blocks, 256, 0, stream>>>(
      zb, x0b, off, edge, dinv, WpT + 2*128*128, perm, scsh, sb, stats, N);
  k_bnfinal<<<1, 128, 0, stream>>>(stats, bn_gamma + 2*H, bn_beta + 2*H, scsh, inv_n);

  // ---- layer 3: zin=sb (raw, BN in gather) -> out (f32, original rows) ----
  k_layer<true,false,true,false><<<lay_blocks, 256, 0, stream>>>(
      sb, x0b, off, edge, dinv, WpT + 3*128*128, perm, scsh, out, nullptr, N);
}